// Round 5
// baseline (15.180 us; speedup 1.0000x reference)
//
#include <hip/hip_runtime.h>
#include <math.h>

#define E_ALL   4100
#define NENT_C  4096
#define DIM     128
#define NBLK_UV 129     // ceil(4100 / 32), 32 rows per block; block 129 does srsc

// Kernel 1 (130 blocks):
//   blocks 0..128 : uv[j] = (e_all[j]·w1, e_all[j]·w2); pbv[blk] = block-max of v
//   block 129     : srsc[0..7] = r_table[x[b,0]]·w1, srsc[8..15] = c_table[x[b,1]]·w1
__global__ __launch_bounds__(256)
void k_uv(const float* __restrict__ e_table,
          const float* __restrict__ anon,
          const float* __restrict__ fc_w,
          const int* __restrict__ x,
          const float* __restrict__ c_table,
          const float* __restrict__ r_table,
          float2* __restrict__ uv,
          float* __restrict__ pbv,
          float* __restrict__ srsc)
{
    const int tid  = threadIdx.x;
    const int lane = tid & 63;
    const int wave = tid >> 6;           // 0..3

    if (blockIdx.x == NBLK_UV) {
        // ---- 16 small dots; wave w handles items w, w+4, w+8, w+12 ----
        const float w1a = fc_w[2*lane];
        const float w1b = fc_w[2*lane + 1];
        const float* rowp[4];
#pragma unroll
        for (int t = 0; t < 4; ++t) {
            const int item = wave + 4*t;
            if (item < 8) rowp[t] = r_table + (size_t)x[2*item] * DIM;
            else          rowp[t] = c_table + (size_t)x[2*(item - 8) + 1] * DIM;
        }
        float p[4];
#pragma unroll
        for (int t = 0; t < 4; ++t) {
            const float2 e2 = *reinterpret_cast<const float2*>(rowp[t] + 2*lane);
            p[t] = fmaf(e2.x, w1a, e2.y * w1b);
        }
#pragma unroll
        for (int o = 32; o; o >>= 1) {
#pragma unroll
            for (int t = 0; t < 4; ++t) p[t] += __shfl_xor(p[t], o);
        }
        if (lane == 0) {
#pragma unroll
            for (int t = 0; t < 4; ++t) srsc[wave + 4*t] = p[t];
        }
        return;
    }

    // ---- main path: 32 rows of u,v per block ----
    const int half = lane >> 5;          // 0: even row, 1: odd row
    const int l32  = lane & 31;
    __shared__ float s_wv[8];

    const float4 w1q = *reinterpret_cast<const float4*>(fc_w + 4*l32);
    const float4 w2q = *reinterpret_cast<const float4*>(fc_w + DIM + 4*l32);

    const int jbase = blockIdx.x * 32 + wave * 8;

    float4 e[4];
#pragma unroll
    for (int i = 0; i < 4; ++i) {
        int j  = jbase + 2*i + half;
        int jc = (j < E_ALL) ? j : (E_ALL - 1);
        const float* row = (jc < NENT_C) ? (e_table + (size_t)jc * DIM)
                                         : (anon + (size_t)(jc - NENT_C) * DIM);
        e[i] = *reinterpret_cast<const float4*>(row + 4*l32);
    }

    float wvmax = -INFINITY;             // meaningful on lanes 0 and 32
#pragma unroll
    for (int i = 0; i < 4; ++i) {
        const int j = jbase + 2*i + half;
        float pu = fmaf(e[i].x, w1q.x, fmaf(e[i].y, w1q.y, fmaf(e[i].z, w1q.z, e[i].w * w1q.w)));
        float pv = fmaf(e[i].x, w2q.x, fmaf(e[i].y, w2q.y, fmaf(e[i].z, w2q.z, e[i].w * w2q.w)));
#pragma unroll
        for (int o = 16; o; o >>= 1) {   // reduce within each 32-lane half
            pu += __shfl_xor(pu, o);
            pv += __shfl_xor(pv, o);
        }
        if (l32 == 0 && j < E_ALL) {
            uv[j] = make_float2(pu, pv);
            wvmax = fmaxf(wvmax, pv);
        }
    }
    if (l32 == 0) s_wv[wave * 2 + half] = wvmax;
    __syncthreads();
    if (tid == 0) {
        float bm = s_wv[0];
#pragma unroll
        for (int k = 1; k < 8; ++k) bm = fmaxf(bm, s_wv[k]);
        pbv[blockIdx.x] = bm;
    }
}

// Kernel 2: single block, 1024 threads. All loads flat & independent.
//   maxfs[b] = 1 / min_j (1 + e^{-u_j}·kb[b]) (1 + e^{-v_j}·mb[b])
//     kb[b] = e^{-(sr_b + b0 + vmax)}, mb[b] = e^{-(sc_b + b0)}
//   loss = mean_b -log(1 - maxfs[b] + 1e-10)
__global__ __launch_bounds__(1024)
void k_final(const float2* __restrict__ uv, const float* __restrict__ pbv,
             const float* __restrict__ srsc,
             const float* __restrict__ fc_b,
             float* __restrict__ out)
{
    __shared__ float s_vmax, s_srsc[16];
    __shared__ float s_q[8][16];
    const int tid  = threadIdx.x;
    const int lane = tid & 63;
    const int wave = tid >> 6;           // 0..15

    // ---- issue the whole uv sweep immediately (one latency level) ----
    const float2 p0 = uv[tid];
    const float2 p1 = uv[tid + 1024];
    const float2 p2 = uv[tid + 2048];
    const float2 p3 = uv[tid + 3072];
    // tail: tids 0..3 take j=4096..4099; others re-read their own j (min is idempotent)
    const float2 p4 = uv[(tid < 4) ? tid + 4096 : tid];

    if (tid < 16) s_srsc[tid] = srsc[tid];

    // vmax over 129 per-block partials (wave 0)
    if (wave == 0) {
        const float a = pbv[lane];
        const float b = pbv[lane + 64];
        const float c = pbv[128];        // same address all lanes -> broadcast
        float vm = fmaxf(fmaxf(a, b), c);
#pragma unroll
        for (int o = 32; o; o >>= 1) vm = fmaxf(vm, __shfl_xor(vm, o));
        if (lane == 0) s_vmax = vm;
    }
    __syncthreads();

    const float b0   = fc_b[0];
    const float vmax = s_vmax;
    float kb[8], mb[8], q[8];
#pragma unroll
    for (int b = 0; b < 8; ++b) {
        kb[b] = __expf(-(s_srsc[b] + b0 + vmax));
        mb[b] = __expf(-(s_srsc[8 + b] + b0));
        q[b]  = INFINITY;
    }

#define PROC(P)                                                   \
    {                                                             \
        const float eu = __expf(-(P).x);                          \
        const float ev = __expf(-(P).y);                          \
        _Pragma("unroll")                                         \
        for (int b = 0; b < 8; ++b) {                             \
            const float t1 = fmaf(eu, kb[b], 1.0f);               \
            const float t2 = fmaf(ev, mb[b], 1.0f);               \
            q[b] = fminf(q[b], t1 * t2);                          \
        }                                                         \
    }
    PROC(p0); PROC(p1); PROC(p2); PROC(p3); PROC(p4);
#undef PROC

#pragma unroll
    for (int b = 0; b < 8; ++b) {
        float t = q[b];
#pragma unroll
        for (int o = 32; o; o >>= 1) t = fminf(t, __shfl_xor(t, o));
        if (lane == 0) s_q[b][wave] = t;
    }
    __syncthreads();
    if (tid < 8) {
        float qm = INFINITY;
#pragma unroll
        for (int w = 0; w < 16; ++w) qm = fminf(qm, s_q[tid][w]);
        const float fs = 1.0f / qm;                         // maxfs[b]
        float t = -logf(1.0f - fs + 1e-10f);
#pragma unroll
        for (int o = 4; o; o >>= 1) t += __shfl_xor(t, o);  // sum lanes 0..7
        if (tid == 0) out[0] = t * 0.125f;
    }
}

extern "C" void kernel_launch(void* const* d_in, const int* in_sizes, int n_in,
                              void* d_out, int out_size, void* d_ws, size_t ws_size,
                              hipStream_t stream) {
    const int*   x        = (const int*)d_in[0];
    const float* anon     = (const float*)d_in[1];
    const float* c_table  = (const float*)d_in[2];
    const float* r_table  = (const float*)d_in[3];
    const float* e_table  = (const float*)d_in[4];
    const float* fc_w     = (const float*)d_in[5];
    const float* fc_b     = (const float*)d_in[6];
    float* out = (float*)d_out;

    float2* uv   = (float2*)d_ws;                 // 4100 float2 (32800 B)
    float*  pbv  = (float*)d_ws + 8448;           // 129 floats
    float*  srsc = (float*)d_ws + 8640;           // 16 floats

    k_uv<<<NBLK_UV + 1, 256, 0, stream>>>(e_table, anon, fc_w, x, c_table, r_table,
                                          uv, pbv, srsc);
    k_final<<<1, 1024, 0, stream>>>(uv, pbv, srsc, fc_b, out);
}

// Round 6
// 15.155 us; speedup vs baseline: 1.0017x; 1.0017x over previous
//
#include <hip/hip_runtime.h>
#include <math.h>

#define E_ALL   4100
#define NENT_C  4096
#define DIM     128
#define NBLK_UV 129     // blocks 0..128 produce uv; block 129 does srsc

// Kernel 1 (130 blocks):
//   blocks 0..127 : 32 rows each, pure e_table path (no clamp, no select)
//   block 128     : rows 4096..4099 from anon (wave 0 only)
//   block 129     : srsc[0..7] = r_table[x[b,0]]·w1, srsc[8..15] = c_table[x[b,1]]·w1
__global__ __launch_bounds__(256)
void k_uv(const float* __restrict__ e_table,
          const float* __restrict__ anon,
          const float* __restrict__ fc_w,
          const int* __restrict__ x,
          const float* __restrict__ c_table,
          const float* __restrict__ r_table,
          float2* __restrict__ uv,
          float* __restrict__ pbv,
          float* __restrict__ srsc)
{
    const int tid  = threadIdx.x;
    const int lane = tid & 63;
    const int wave = tid >> 6;           // 0..3

    if (blockIdx.x == NBLK_UV) {
        // ---- 16 small dots; wave w handles items w, w+4, w+8, w+12 ----
        const float w1a = fc_w[2*lane];
        const float w1b = fc_w[2*lane + 1];
        const float* rowp[4];
#pragma unroll
        for (int t = 0; t < 4; ++t) {
            const int item = wave + 4*t;
            if (item < 8) rowp[t] = r_table + (size_t)x[2*item] * DIM;
            else          rowp[t] = c_table + (size_t)x[2*(item - 8) + 1] * DIM;
        }
        float p[4];
#pragma unroll
        for (int t = 0; t < 4; ++t) {
            const float2 e2 = *reinterpret_cast<const float2*>(rowp[t] + 2*lane);
            p[t] = fmaf(e2.x, w1a, e2.y * w1b);
        }
#pragma unroll
        for (int o = 32; o; o >>= 1) {
#pragma unroll
            for (int t = 0; t < 4; ++t) p[t] += __shfl_xor(p[t], o);
        }
        if (lane == 0) {
#pragma unroll
            for (int t = 0; t < 4; ++t) srsc[wave + 4*t] = p[t];
        }
        return;
    }

    // ---- uv path: 32 rows per block (block 128: 4 anon rows) ----
    const int half = lane >> 5;          // 0: even row, 1: odd row
    const int l32  = lane & 31;
    __shared__ float s_wv[8];

    const float4 w1q = *reinterpret_cast<const float4*>(fc_w + 4*l32);
    const float4 w2q = *reinterpret_cast<const float4*>(fc_w + DIM + 4*l32);

    float wvmax = -INFINITY;             // meaningful on lanes 0 and 32

    if (blockIdx.x < 128) {
        const int jbase = blockIdx.x * 32 + wave * 8;
        // one base address; 4 loads at immediate offsets (2 rows apart = 1024 B)
        const float* base = e_table + (size_t)(jbase + half) * DIM + 4*l32;
        float4 e[4];
#pragma unroll
        for (int i = 0; i < 4; ++i)
            e[i] = *reinterpret_cast<const float4*>(base + (size_t)(2*i) * DIM);

#pragma unroll
        for (int i = 0; i < 4; ++i) {
            float pu = fmaf(e[i].x, w1q.x, fmaf(e[i].y, w1q.y, fmaf(e[i].z, w1q.z, e[i].w * w1q.w)));
            float pv = fmaf(e[i].x, w2q.x, fmaf(e[i].y, w2q.y, fmaf(e[i].z, w2q.z, e[i].w * w2q.w)));
#pragma unroll
            for (int o = 16; o; o >>= 1) {   // reduce within each 32-lane half
                pu += __shfl_xor(pu, o);
                pv += __shfl_xor(pv, o);
            }
            if (l32 == 0) {
                uv[jbase + 2*i + half] = make_float2(pu, pv);
                wvmax = fmaxf(wvmax, pv);
            }
        }
    } else if (wave == 0) {
        // block 128: rows 4096..4099 live in anon[0..3]
        const float* base = anon + (size_t)half * DIM + 4*l32;
        float4 e[2];
#pragma unroll
        for (int i = 0; i < 2; ++i)
            e[i] = *reinterpret_cast<const float4*>(base + (size_t)(2*i) * DIM);
#pragma unroll
        for (int i = 0; i < 2; ++i) {
            float pu = fmaf(e[i].x, w1q.x, fmaf(e[i].y, w1q.y, fmaf(e[i].z, w1q.z, e[i].w * w1q.w)));
            float pv = fmaf(e[i].x, w2q.x, fmaf(e[i].y, w2q.y, fmaf(e[i].z, w2q.z, e[i].w * w2q.w)));
#pragma unroll
            for (int o = 16; o; o >>= 1) {
                pu += __shfl_xor(pu, o);
                pv += __shfl_xor(pv, o);
            }
            if (l32 == 0) {
                uv[4096 + 2*i + half] = make_float2(pu, pv);
                wvmax = fmaxf(wvmax, pv);
            }
        }
    }

    if (l32 == 0) s_wv[wave * 2 + half] = wvmax;
    __syncthreads();
    if (tid == 0) {
        float bm = s_wv[0];
#pragma unroll
        for (int k = 1; k < 8; ++k) bm = fmaxf(bm, s_wv[k]);
        pbv[blockIdx.x] = bm;
    }
}

// Kernel 2: single block, 1024 threads. All loads flat & independent.
//   maxfs[b] = 1 / min_j (1 + e^{-u_j}·kb[b]) (1 + e^{-v_j}·mb[b])
//     kb[b] = e^{-(sr_b + b0 + vmax)}, mb[b] = e^{-(sc_b + b0)}
//   loss = mean_b -log(1 - maxfs[b] + 1e-10)
__global__ __launch_bounds__(1024)
void k_final(const float2* __restrict__ uv, const float* __restrict__ pbv,
             const float* __restrict__ srsc,
             const float* __restrict__ fc_b,
             float* __restrict__ out)
{
    __shared__ float s_vmax, s_srsc[16];
    __shared__ float s_q[8][16];
    const int tid  = threadIdx.x;
    const int lane = tid & 63;
    const int wave = tid >> 6;           // 0..15

    // ---- issue the whole uv sweep immediately (one latency level) ----
    const float2 p0 = uv[tid];
    const float2 p1 = uv[tid + 1024];
    const float2 p2 = uv[tid + 2048];
    const float2 p3 = uv[tid + 3072];
    // tail: tids 0..3 take j=4096..4099; others re-read their own j (min is idempotent)
    const float2 p4 = uv[(tid < 4) ? tid + 4096 : tid];

    if (tid < 16) s_srsc[tid] = srsc[tid];

    // vmax over 129 per-block partials (wave 0)
    if (wave == 0) {
        const float a = pbv[lane];
        const float b = pbv[lane + 64];
        const float c = pbv[128];        // same address all lanes -> broadcast
        float vm = fmaxf(fmaxf(a, b), c);
#pragma unroll
        for (int o = 32; o; o >>= 1) vm = fmaxf(vm, __shfl_xor(vm, o));
        if (lane == 0) s_vmax = vm;
    }
    __syncthreads();

    const float b0   = fc_b[0];
    const float vmax = s_vmax;
    float kb[8], mb[8], q[8];
#pragma unroll
    for (int b = 0; b < 8; ++b) {
        kb[b] = __expf(-(s_srsc[b] + b0 + vmax));
        mb[b] = __expf(-(s_srsc[8 + b] + b0));
        q[b]  = INFINITY;
    }

#define PROC(P)                                                   \
    {                                                             \
        const float eu = __expf(-(P).x);                          \
        const float ev = __expf(-(P).y);                          \
        _Pragma("unroll")                                         \
        for (int b = 0; b < 8; ++b) {                             \
            const float t1 = fmaf(eu, kb[b], 1.0f);               \
            const float t2 = fmaf(ev, mb[b], 1.0f);               \
            q[b] = fminf(q[b], t1 * t2);                          \
        }                                                         \
    }
    PROC(p0); PROC(p1); PROC(p2); PROC(p3); PROC(p4);
#undef PROC

#pragma unroll
    for (int b = 0; b < 8; ++b) {
        float t = q[b];
#pragma unroll
        for (int o = 32; o; o >>= 1) t = fminf(t, __shfl_xor(t, o));
        if (lane == 0) s_q[b][wave] = t;
    }
    __syncthreads();
    if (tid < 8) {
        float qm = INFINITY;
#pragma unroll
        for (int w = 0; w < 16; ++w) qm = fminf(qm, s_q[tid][w]);
        const float fs = 1.0f / qm;                         // maxfs[b]
        float t = -logf(1.0f - fs + 1e-10f);
#pragma unroll
        for (int o = 4; o; o >>= 1) t += __shfl_xor(t, o);  // sum lanes 0..7
        if (tid == 0) out[0] = t * 0.125f;
    }
}

extern "C" void kernel_launch(void* const* d_in, const int* in_sizes, int n_in,
                              void* d_out, int out_size, void* d_ws, size_t ws_size,
                              hipStream_t stream) {
    const int*   x        = (const int*)d_in[0];
    const float* anon     = (const float*)d_in[1];
    const float* c_table  = (const float*)d_in[2];
    const float* r_table  = (const float*)d_in[3];
    const float* e_table  = (const float*)d_in[4];
    const float* fc_w     = (const float*)d_in[5];
    const float* fc_b     = (const float*)d_in[6];
    float* out = (float*)d_out;

    float2* uv   = (float2*)d_ws;                 // 4100 float2 (32800 B)
    float*  pbv  = (float*)d_ws + 8448;           // 129 floats
    float*  srsc = (float*)d_ws + 8640;           // 16 floats

    k_uv<<<NBLK_UV + 1, 256, 0, stream>>>(e_table, anon, fc_w, x, c_table, r_table,
                                          uv, pbv, srsc);
    k_final<<<1, 1024, 0, stream>>>(uv, pbv, srsc, fc_b, out);
}